// Round 15
// baseline (141.623 us; speedup 1.0000x reference)
//
#include <hip/hip_runtime.h>
#include <hip/hip_bf16.h>

#define B_DIM 2048
#define S_DIM 32768
#define G_DIM 4096
#define E_DIM 1024
#define KSPLIT 4
#define KCHUNK (G_DIM / KSPLIT)

typedef __bf16 bf16x8 __attribute__((ext_vector_type(8)));
typedef float f32x4 __attribute__((ext_vector_type(4)));

__device__ __forceinline__ unsigned short f2bf(float f) {
  unsigned int u = __builtin_bit_cast(unsigned int, f);
  u += 0x7FFFu + ((u >> 16) & 1u);   // round-to-nearest-even (no NaN inputs here)
  return (unsigned short)(u >> 16);
}

__device__ __forceinline__ float bfl(unsigned u) {
  return __builtin_bit_cast(float, u << 16);
}
__device__ __forceinline__ float bfh(unsigned u) {
  return __builtin_bit_cast(float, u & 0xFFFF0000u);
}

__device__ __forceinline__ void async16(void* lds, const void* g) {
  __builtin_amdgcn_global_load_lds(
      (const __attribute__((address_space(1))) unsigned int*)g,
      (__attribute__((address_space(3))) unsigned int*)lds, 16, 0, 0);
}

// Non-returning LDS float atomic add (ds_add_f32). Invisible to the
// compiler's waitcnt model: must be drained with an explicit
// s_waitcnt lgkmcnt(0) before any barrier that readers wait on.
__device__ __forceinline__ void lds_add(float* p, float v) {
  unsigned off = (unsigned)(size_t)(__attribute__((address_space(3))) float*)p;
  asm volatile("ds_add_f32 %0, %1" :: "v"(off), "v"(v));
}

// ---------------- prep: conv_w + setup_meta + setup_runs in ONE kernel ------
// blocks [0,4096): W f32->bf16 (1024 elems each)
// blocks [4096,4224): meta1[s] = perm|orflag|bf16(cm)<<16 (256 each)
// blocks [4224,4228): per-32-window run-head mask + first group
__global__ __launch_bounds__(256) void prep(
    const float* __restrict__ W, const float* __restrict__ w_elem,
    const int* __restrict__ perm, const int* __restrict__ segid,
    const int* __restrict__ agg, unsigned short* __restrict__ Wb,
    unsigned* __restrict__ meta1, unsigned* __restrict__ metaH,
    unsigned short* __restrict__ metaG) {
  const int blk = blockIdx.x;
  const int tid = threadIdx.x;
  if (blk < 4096) {  // conv_w
    size_t i = ((size_t)blk * 256 + tid) * 4;
    float4 v = *reinterpret_cast<const float4*>(W + i);
    ushort4 o;
    o.x = f2bf(v.x);
    o.y = f2bf(v.y);
    o.z = f2bf(v.z);
    o.w = f2bf(v.w);
    *reinterpret_cast<ushort4*>(Wb + i) = o;
  } else if (blk < 4224) {  // setup_meta
    int s = (blk - 4096) * 256 + tid;
    int g = segid[s];
    int a = agg[g];
    float cm = (a == 0) ? 1.0f : (a == 2 ? w_elem[s] : 0.0f);
    meta1[s] = (unsigned)perm[s] | (a == 1 ? 0x8000u : 0u) |
               ((unsigned)f2bf(cm) << 16);
  } else {  // setup_runs
    int t = (blk - 4224) * 256 + tid;
    int s0 = t * 32;
    int prev = (s0 == 0) ? -1 : segid[s0 - 1];
    unsigned m = 0;
#pragma unroll
    for (int c = 0; c < 8; ++c) {
      int4 gw = *reinterpret_cast<const int4*>(segid + s0 + c * 4);
      if (gw.x != prev) m |= 1u << (c * 4 + 0);
      if (gw.y != gw.x) m |= 1u << (c * 4 + 1);
      if (gw.z != gw.y) m |= 1u << (c * 4 + 2);
      if (gw.w != gw.z) m |= 1u << (c * 4 + 3);
      prev = gw.w;
    }
    metaH[t] = m;
    metaG[t] = (unsigned short)segid[s0];
  }
}

// ---------------- stage 1: 1 row/block, 2 barriers, wave-scan combine ------
// R12 structure; all walk metadata (meta1 -> 8 x uint4 regs, metaH/metaG/agg)
// hoisted ABOVE the stage loop so the post-barrier walk starts with zero
// outstanding global loads (meta is oldest in the vmcnt FIFO and drains
// under the stage loop's own consumption).
__global__ __launch_bounds__(1024, 8) void seg_reduce(
    const float* __restrict__ x, const unsigned* __restrict__ meta1,
    const unsigned* __restrict__ metaH, const unsigned short* __restrict__ metaG,
    const int* __restrict__ agg, unsigned short* __restrict__ y) {
  __shared__ __align__(16) unsigned short xrow[S_DIM];  // 64 KB (bf16)
  __shared__ float acc[G_DIM];                          // 16 KB
  const int t = threadIdx.x;
  const int b = blockIdx.x;
  const unsigned lane = t & 63;

  // hoisted metadata: issue these loads FIRST (oldest in vmcnt FIFO)
  const unsigned mrun = metaH[t];
  const int g0 = metaG[t];
  uint4 mr[8];
#pragma unroll
  for (int q = 0; q < 8; ++q)
    mr[q] = *reinterpret_cast<const uint4*>(meta1 + t * 32 + q * 4);
  const bool fp = (mrun & 1u) != 0;  // run head exactly at my window start
  const int F = (mrun != 0);

#pragma unroll
  for (int i = 0; i < G_DIM / 1024; ++i) acc[t + i * 1024] = 0.0f;

  // stage full row as bf16: coalesced float4 load -> packed cvt -> 8B ds_write
  const float4* xg = reinterpret_cast<const float4*>(x + (size_t)b * S_DIM);
#pragma unroll
  for (int i = 0; i < S_DIM / 4 / 1024; ++i) {
    float4 v = xg[i * 1024 + t];
    unsigned short h0 = __builtin_bit_cast(unsigned short, (__bf16)v.x);
    unsigned short h1 = __builtin_bit_cast(unsigned short, (__bf16)v.y);
    unsigned short h2 = __builtin_bit_cast(unsigned short, (__bf16)v.z);
    unsigned short h3 = __builtin_bit_cast(unsigned short, (__bf16)v.w);
    uint2 p;
    p.x = (unsigned)h0 | ((unsigned)h1 << 16);
    p.y = (unsigned)h2 | ((unsigned)h3 << 16);
    *reinterpret_cast<uint2*>(&xrow[(i * 1024 + t) * 4]) = p;
  }
  __syncthreads();  // B1: xrow + acc zero visible

  float sum = 0.0f, lead = 0.0f;
  int g = g0;
  int nf = 0;

#pragma unroll
  for (int q = 0; q < 8; ++q) {
    unsigned m4[4] = {mr[q].x, mr[q].y, mr[q].z, mr[q].w};
    unsigned short xu[4];
#pragma unroll
    for (int j = 0; j < 4; ++j) xu[j] = xrow[m4[j] & 0x7FFF];
    const unsigned mh = mrun >> (q * 4);
#pragma unroll
    for (int j = 0; j < 4; ++j) {
      if (q * 4 + j > 0 && (mh & (1u << j))) {  // run head: close prev run
        if (nf == 0 && !fp) {
          lead = sum;  // portion of a run that started in an earlier thread
        } else {
          acc[g] = sum;  // run started & ended inside my window: exclusive
        }
        ++nf;
        sum = 0.0f;
        ++g;
      }
      float xv = bfl((unsigned)xu[j]);
      float cm = bfh(m4[j]);
      float v = (m4[j] & 0x8000u) ? (xu[j] ? 1.0f : 0.0f) : xv * cm;
      sum += v;
    }
  }
  // per-thread summary: myLead = collectable-by-predecessor portion,
  // sum = trailing-run partial (group g), F = has a run head (stops scan)
  float myLead = fp ? 0.0f : (nf == 0 ? sum : lead);

  // segmented suffix scan over lanes
  float s = myLead;
  int o = !F;
#pragma unroll
  for (int d = 1; d <= 32; d <<= 1) {
    float sd = __shfl_down(s, d);
    int od = __shfl_down(o, d);
    const bool valid = lane + d < 64;
    sd = valid ? sd : 0.0f;
    od = valid ? od : 1;  // virtual lanes: open, contribute 0
    s += o ? sd : 0.0f;
    o &= od;
  }
  float s1 = __shfl_down(s, 1);
  int o1 = __shfl_down(o, 1);
  if (lane == 63) {
    s1 = 0.0f;
    o1 = 1;
  }

  if (F) {  // owner of my trailing run
    float tot = sum + s1;
    if (o1) {
      lds_add(&acc[g], tot);  // run continues into the next wave
    } else {
      acc[g] = tot;  // run closed within this wave: exclusive write
    }
  }
  if (lane == 0 && !fp) {
    lds_add(&acc[g0], s);  // wave-leading portion of an incoming run
  }

  // Drain asm ds_adds (invisible to compiler waitcnt model) before barrier.
  asm volatile("s_waitcnt lgkmcnt(0)" ::: "memory");
  __syncthreads();  // B2

#pragma unroll
  for (int i = 0; i < G_DIM / 1024; ++i) {
    int g2 = t + i * 1024;
    float v = acc[g2];
    if (agg[g2] == 1) v = (v > 0.0f) ? 1.0f : 0.0f;  // acc holds nnz count
    v = fmaxf(v, 0.0f);                               // relu
    y[(size_t)b * G_DIM + g2] = f2bf(v);
  }
}

// ---------------- stage 2a: split-K GEMM, 128x128 tile (m97 structure) -----
__global__ __launch_bounds__(256) void gemm_bt(
    const unsigned short* __restrict__ A,   // y bf16 [B_DIM][G_DIM]
    const unsigned short* __restrict__ Bw,  // W bf16 [E_DIM][G_DIM]
    unsigned short* __restrict__ part) {    // [KSPLIT][B_DIM][E_DIM] bf16
  __shared__ __align__(16) unsigned short As[128 * 64];  // 16 KB
  __shared__ __align__(16) unsigned short Bs[128 * 64];  // 16 KB
  const int t = threadIdx.x;
  const int lane = t & 63;
  const int wid = t >> 6;
  const int wr = wid >> 1;  // wave row (M): 0..1, owns 64 rows
  const int wc = wid & 1;   // wave col (N): 0..1, owns 64 cols
  const int row0 = blockIdx.y * 128;
  const int col0 = blockIdx.x * 128;
  const int kc = blockIdx.z;

  // staging: round i covers LDS bytes i*4096 + t*16 -> row = i*32 + (t>>3),
  // slot = t&7. Inverse-swizzled k offset (round-invariant: 32 % 8 == 0).
  const int r_ = t >> 3;  // 0..31 (round-local row base)
  const int ksw = ((t & 7) ^ (r_ & 7)) * 8;  // elements
  const unsigned short* Ag[4];
  const unsigned short* Bg[4];
#pragma unroll
  for (int i = 0; i < 4; ++i) {
    Ag[i] = A + (size_t)(row0 + i * 32 + r_) * G_DIM + ksw;
    Bg[i] = Bw + (size_t)(col0 + i * 32 + r_) * G_DIM + ksw;
  }
  char* AsB = (char*)As;
  char* BsB = (char*)Bs;
  char* dA[4];
  char* dB[4];
#pragma unroll
  for (int i = 0; i < 4; ++i) {
    dA[i] = AsB + i * 4096 + wid * 1024;  // wave-uniform LDS dst bases
    dB[i] = BsB + i * 4096 + wid * 1024;
  }

  const int lm = lane & 15;
  const int lk = lane >> 4;  // 0..3

  f32x4 acc[4][4] = {};

  for (int kt = kc * KCHUNK; kt < (kc + 1) * KCHUNK; kt += 64) {
#pragma unroll
    for (int i = 0; i < 4; ++i) {
      async16(dA[i], Ag[i] + kt);
      async16(dB[i], Bg[i] + kt);
    }
    __syncthreads();  // drains vmcnt before barrier
#pragma unroll
    for (int kk = 0; kk < 2; ++kk) {
      bf16x8 af[4], bfr[4];
#pragma unroll
      for (int m = 0; m < 4; ++m) {
        int row = wr * 64 + m * 16 + lm;
        int slot = (kk * 4 + lk) ^ (row & 7);
        af[m] = *(const bf16x8*)(AsB + row * 128 + slot * 16);
      }
#pragma unroll
      for (int n = 0; n < 4; ++n) {
        int row = wc * 64 + n * 16 + lm;
        int slot = (kk * 4 + lk) ^ (row & 7);
        bfr[n] = *(const bf16x8*)(BsB + row * 128 + slot * 16);
      }
#pragma unroll
      for (int m = 0; m < 4; ++m)
#pragma unroll
        for (int n = 0; n < 4; ++n)
          acc[m][n] = __builtin_amdgcn_mfma_f32_16x16x32_bf16(af[m], bfr[n],
                                                              acc[m][n], 0, 0, 0);
    }
    __syncthreads();  // protect LDS before next stage
  }

  // C/D layout: col = lane&15, row = (lane>>4)*4 + reg
  unsigned short* P = part + (size_t)kc * B_DIM * E_DIM;
#pragma unroll
  for (int m = 0; m < 4; ++m) {
    int r = row0 + wr * 64 + m * 16 + lk * 4;
#pragma unroll
    for (int n = 0; n < 4; ++n) {
      int c = col0 + wc * 64 + n * 16 + lm;
#pragma unroll
      for (int q = 0; q < 4; ++q) {
        P[(size_t)(r + q) * E_DIM + c] = f2bf(acc[m][n][q]);
      }
    }
  }
}

// ---------------- stage 2b: reduce bf16 split-K partials -------------------
__global__ __launch_bounds__(256) void reduce_part(
    const unsigned short* __restrict__ part, float* __restrict__ C) {
  const size_t i = ((size_t)blockIdx.x * 256 + threadIdx.x) * 8;
  const size_t n = (size_t)B_DIM * E_DIM;
  float e[8] = {};
#pragma unroll
  for (int p = 0; p < KSPLIT; ++p) {
    uint4 v = *reinterpret_cast<const uint4*>(part + p * n + i);
    unsigned w[4] = {v.x, v.y, v.z, v.w};
#pragma unroll
    for (int q = 0; q < 4; ++q) {
      e[2 * q] += bfl(w[q]);
      e[2 * q + 1] += bfh(w[q]);
    }
  }
  float4 o0 = {e[0], e[1], e[2], e[3]};
  float4 o1 = {e[4], e[5], e[6], e[7]};
  *reinterpret_cast<float4*>(C + i) = o0;
  *reinterpret_cast<float4*>(C + i + 4) = o1;
}

extern "C" void kernel_launch(void* const* d_in, const int* in_sizes, int n_in,
                              void* d_out, int out_size, void* d_ws, size_t ws_size,
                              hipStream_t stream) {
  const float* x = (const float*)d_in[0];
  const float* W = (const float*)d_in[1];
  const float* w_elem = (const float*)d_in[2];
  const int* perm = (const int*)d_in[3];
  const int* segid = (const int*)d_in[4];
  const int* agg = (const int*)d_in[5];
  float* out = (float*)d_out;

  char* ws = (char*)d_ws;
  unsigned short* y = (unsigned short*)ws;  // B*G bf16 = 16 MB
  unsigned short* Wb =
      (unsigned short*)(ws + (size_t)B_DIM * G_DIM * 2);  // E*G bf16 = 8 MB
  unsigned short* part =
      (unsigned short*)(ws + (size_t)B_DIM * G_DIM * 2 +
                        (size_t)E_DIM * G_DIM * 2);  // 4*B*E bf16 = 16 MB
  unsigned* meta1 =
      (unsigned*)((char*)part + (size_t)KSPLIT * B_DIM * E_DIM * 2);
  unsigned* metaH = (unsigned*)((char*)meta1 + (size_t)S_DIM * 4);
  unsigned short* metaG = (unsigned short*)((char*)metaH + (S_DIM / 32) * 4);

  hipLaunchKernelGGL(prep, dim3(4228), dim3(256), 0, stream, W, w_elem, perm,
                     segid, agg, Wb, meta1, metaH, metaG);
  hipLaunchKernelGGL(seg_reduce, dim3(B_DIM), dim3(1024), 0, stream, x, meta1,
                     metaH, metaG, agg, y);
  hipLaunchKernelGGL(gemm_bt, dim3(E_DIM / 128, B_DIM / 128, KSPLIT),
                     dim3(256), 0, stream, y, Wb, part);
  hipLaunchKernelGGL(reduce_part,
                     dim3(((size_t)B_DIM * E_DIM / 8) / 256), dim3(256), 0,
                     stream, part, out);
}

// Round 16
// 113.817 us; speedup vs baseline: 1.2443x; 1.2443x over previous
//
#include <hip/hip_runtime.h>
#include <hip/hip_bf16.h>

#define B_DIM 2048
#define S_DIM 32768
#define G_DIM 4096
#define E_DIM 1024
#define KSPLIT 4
#define KCHUNK (G_DIM / KSPLIT)

typedef __bf16 bf16x8 __attribute__((ext_vector_type(8)));
typedef float f32x4 __attribute__((ext_vector_type(4)));

__device__ __forceinline__ unsigned short f2bf(float f) {
  unsigned int u = __builtin_bit_cast(unsigned int, f);
  u += 0x7FFFu + ((u >> 16) & 1u);   // round-to-nearest-even (no NaN inputs here)
  return (unsigned short)(u >> 16);
}

__device__ __forceinline__ float bfl(unsigned u) {
  return __builtin_bit_cast(float, u << 16);
}
__device__ __forceinline__ float bfh(unsigned u) {
  return __builtin_bit_cast(float, u & 0xFFFF0000u);
}

__device__ __forceinline__ void async16(void* lds, const void* g) {
  __builtin_amdgcn_global_load_lds(
      (const __attribute__((address_space(1))) unsigned int*)g,
      (__attribute__((address_space(3))) unsigned int*)lds, 16, 0, 0);
}

// Non-returning LDS float atomic add (ds_add_f32). Invisible to the
// compiler's waitcnt model: must be drained with an explicit
// s_waitcnt lgkmcnt(0) before any barrier that readers wait on.
__device__ __forceinline__ void lds_add(float* p, float v) {
  unsigned off = (unsigned)(size_t)(__attribute__((address_space(3))) float*)p;
  asm volatile("ds_add_f32 %0, %1" :: "v"(off), "v"(v));
}

// ---------------- setup: meta1 + run-head masks in ONE kernel ---------------
// blocks [0,128):  meta1[s] = perm|orflag|bf16(cm)<<16   (256 elems each)
// blocks [128,132): per-32-window run-head mask + first group
__global__ __launch_bounds__(256) void setup(
    const float* __restrict__ w_elem, const int* __restrict__ perm,
    const int* __restrict__ segid, const int* __restrict__ agg,
    unsigned* __restrict__ meta1, unsigned* __restrict__ metaH,
    unsigned short* __restrict__ metaG) {
  const int blk = blockIdx.x;
  const int tid = threadIdx.x;
  if (blk < 128) {  // setup_meta
    int s = blk * 256 + tid;
    int g = segid[s];
    int a = agg[g];
    float cm = (a == 0) ? 1.0f : (a == 2 ? w_elem[s] : 0.0f);
    meta1[s] = (unsigned)perm[s] | (a == 1 ? 0x8000u : 0u) |
               ((unsigned)f2bf(cm) << 16);
  } else {  // setup_runs
    int t = (blk - 128) * 256 + tid;
    int s0 = t * 32;
    int prev = (s0 == 0) ? -1 : segid[s0 - 1];
    unsigned m = 0;
#pragma unroll
    for (int c = 0; c < 8; ++c) {
      int4 gw = *reinterpret_cast<const int4*>(segid + s0 + c * 4);
      if (gw.x != prev) m |= 1u << (c * 4 + 0);
      if (gw.y != gw.x) m |= 1u << (c * 4 + 1);
      if (gw.z != gw.y) m |= 1u << (c * 4 + 2);
      if (gw.w != gw.z) m |= 1u << (c * 4 + 3);
      prev = gw.w;
    }
    metaH[t] = m;
    metaG[t] = (unsigned short)segid[s0];
  }
}

// ---------------- stage 1: 1 row/block, 2 barriers, wave-scan combine ------
// seg body = R14 verbatim (best measured; R15's hoisted-meta variant spilled).
// Blocks [B_DIM, B_DIM+1024) instead convert W f32->bf16 (independent work
// folded into this grid: hides conv traffic under seg's idle memory slots
// and saves a dispatch; gemm_bt, the only Wb consumer, launches after).
__global__ __launch_bounds__(1024, 8) void seg_reduce(
    const float* __restrict__ x, const unsigned* __restrict__ meta1,
    const unsigned* __restrict__ metaH, const unsigned short* __restrict__ metaG,
    const int* __restrict__ agg, unsigned short* __restrict__ y,
    const float* __restrict__ W, unsigned short* __restrict__ Wb) {
  __shared__ __align__(16) unsigned short xrow[S_DIM];  // 64 KB (bf16)
  __shared__ float acc[G_DIM];                          // 16 KB
  const int t = threadIdx.x;
  const int b = blockIdx.x;
  const unsigned lane = t & 63;

  if (b >= B_DIM) {  // conv_w block (uniform branch, no barriers used)
    size_t i = ((size_t)(b - B_DIM) * 1024 + t) * 4;
    float4 v = *reinterpret_cast<const float4*>(W + i);
    ushort4 o;
    o.x = f2bf(v.x);
    o.y = f2bf(v.y);
    o.z = f2bf(v.z);
    o.w = f2bf(v.w);
    *reinterpret_cast<ushort4*>(Wb + i) = o;
    return;
  }

#pragma unroll
  for (int i = 0; i < G_DIM / 1024; ++i) acc[t + i * 1024] = 0.0f;

  const unsigned mrun = metaH[t];
  const bool fp = (mrun & 1u) != 0;  // run head exactly at my window start
  const int g0 = metaG[t];
  int g = g0;

  // stage full row as bf16: coalesced float4 load -> packed cvt -> 8B ds_write
  const float4* xg = reinterpret_cast<const float4*>(x + (size_t)b * S_DIM);
#pragma unroll
  for (int i = 0; i < S_DIM / 4 / 1024; ++i) {
    float4 v = xg[i * 1024 + t];
    unsigned short h0 = __builtin_bit_cast(unsigned short, (__bf16)v.x);
    unsigned short h1 = __builtin_bit_cast(unsigned short, (__bf16)v.y);
    unsigned short h2 = __builtin_bit_cast(unsigned short, (__bf16)v.z);
    unsigned short h3 = __builtin_bit_cast(unsigned short, (__bf16)v.w);
    uint2 p;
    p.x = (unsigned)h0 | ((unsigned)h1 << 16);
    p.y = (unsigned)h2 | ((unsigned)h3 << 16);
    *reinterpret_cast<uint2*>(&xrow[(i * 1024 + t) * 4]) = p;
  }
  __syncthreads();  // B1: xrow + acc zero visible

  const int s0 = t * 32;
  float sum = 0.0f, lead = 0.0f;
  int nf = 0;

  for (int h = 0; h < 2; ++h) {  // two halves of 16 elems
    const int sb = s0 + h * 16;
    uint4 ma = *reinterpret_cast<const uint4*>(meta1 + sb);
    uint4 mb = *reinterpret_cast<const uint4*>(meta1 + sb + 4);
    uint4 mc = *reinterpret_cast<const uint4*>(meta1 + sb + 8);
    uint4 md = *reinterpret_cast<const uint4*>(meta1 + sb + 12);
    unsigned m[16] = {ma.x, ma.y, ma.z, ma.w, mb.x, mb.y, mb.z, mb.w,
                      mc.x, mc.y, mc.z, mc.w, md.x, md.y, md.z, md.w};
    unsigned short xu[16];
#pragma unroll
    for (int j = 0; j < 16; ++j) xu[j] = xrow[m[j] & 0x7FFF];
    const unsigned mh = mrun >> (h * 16);
#pragma unroll
    for (int j = 0; j < 16; ++j) {
      if (h + j > 0 && (mh & (1u << j))) {  // run head: close previous run
        if (nf == 0 && !fp) {
          lead = sum;  // portion of a run that started in an earlier thread
        } else {
          acc[g] = sum;  // run started & ended inside my window: exclusive
        }
        ++nf;
        sum = 0.0f;
        ++g;
      }
      float xv = bfl((unsigned)xu[j]);
      float cm = bfh(m[j]);
      float v = (m[j] & 0x8000u) ? (xu[j] ? 1.0f : 0.0f) : xv * cm;
      sum += v;
    }
  }
  // per-thread summary: myLead = collectable-by-predecessor portion,
  // sum = trailing-run partial (group g), F = has a run head (stops scan)
  float myLead = fp ? 0.0f : (nf == 0 ? sum : lead);
  const int F = (mrun != 0);

  // segmented suffix scan over lanes
  float s = myLead;
  int o = !F;
#pragma unroll
  for (int d = 1; d <= 32; d <<= 1) {
    float sd = __shfl_down(s, d);
    int od = __shfl_down(o, d);
    const bool valid = lane + d < 64;
    sd = valid ? sd : 0.0f;
    od = valid ? od : 1;  // virtual lanes: open, contribute 0
    s += o ? sd : 0.0f;
    o &= od;
  }
  float s1 = __shfl_down(s, 1);
  int o1 = __shfl_down(o, 1);
  if (lane == 63) {
    s1 = 0.0f;
    o1 = 1;
  }

  if (mrun != 0) {  // owner of my trailing run
    float tot = sum + s1;
    if (o1) {
      lds_add(&acc[g], tot);  // run continues into the next wave
    } else {
      acc[g] = tot;  // run closed within this wave: exclusive write
    }
  }
  if (lane == 0 && !fp) {
    lds_add(&acc[g0], s);  // wave-leading portion of an incoming run
  }

  // Drain asm ds_adds (invisible to compiler waitcnt model) before barrier.
  asm volatile("s_waitcnt lgkmcnt(0)" ::: "memory");
  __syncthreads();  // B2

#pragma unroll
  for (int i = 0; i < G_DIM / 1024; ++i) {
    int g2 = t + i * 1024;
    float v = acc[g2];
    if (agg[g2] == 1) v = (v > 0.0f) ? 1.0f : 0.0f;  // acc holds nnz count
    v = fmaxf(v, 0.0f);                               // relu
    y[(size_t)b * G_DIM + g2] = f2bf(v);
  }
}

// ---------------- stage 2a: split-K GEMM, 128x128 tile (m97 structure) -----
__global__ __launch_bounds__(256) void gemm_bt(
    const unsigned short* __restrict__ A,   // y bf16 [B_DIM][G_DIM]
    const unsigned short* __restrict__ Bw,  // W bf16 [E_DIM][G_DIM]
    unsigned short* __restrict__ part) {    // [KSPLIT][B_DIM][E_DIM] bf16
  __shared__ __align__(16) unsigned short As[128 * 64];  // 16 KB
  __shared__ __align__(16) unsigned short Bs[128 * 64];  // 16 KB
  const int t = threadIdx.x;
  const int lane = t & 63;
  const int wid = t >> 6;
  const int wr = wid >> 1;  // wave row (M): 0..1, owns 64 rows
  const int wc = wid & 1;   // wave col (N): 0..1, owns 64 cols
  const int row0 = blockIdx.y * 128;
  const int col0 = blockIdx.x * 128;
  const int kc = blockIdx.z;

  // staging: round i covers LDS bytes i*4096 + t*16 -> row = i*32 + (t>>3),
  // slot = t&7. Inverse-swizzled k offset (round-invariant: 32 % 8 == 0).
  const int r_ = t >> 3;  // 0..31 (round-local row base)
  const int ksw = ((t & 7) ^ (r_ & 7)) * 8;  // elements
  const unsigned short* Ag[4];
  const unsigned short* Bg[4];
#pragma unroll
  for (int i = 0; i < 4; ++i) {
    Ag[i] = A + (size_t)(row0 + i * 32 + r_) * G_DIM + ksw;
    Bg[i] = Bw + (size_t)(col0 + i * 32 + r_) * G_DIM + ksw;
  }
  char* AsB = (char*)As;
  char* BsB = (char*)Bs;
  char* dA[4];
  char* dB[4];
#pragma unroll
  for (int i = 0; i < 4; ++i) {
    dA[i] = AsB + i * 4096 + wid * 1024;  // wave-uniform LDS dst bases
    dB[i] = BsB + i * 4096 + wid * 1024;
  }

  const int lm = lane & 15;
  const int lk = lane >> 4;  // 0..3

  f32x4 acc[4][4] = {};

  for (int kt = kc * KCHUNK; kt < (kc + 1) * KCHUNK; kt += 64) {
#pragma unroll
    for (int i = 0; i < 4; ++i) {
      async16(dA[i], Ag[i] + kt);
      async16(dB[i], Bg[i] + kt);
    }
    __syncthreads();  // drains vmcnt before barrier
#pragma unroll
    for (int kk = 0; kk < 2; ++kk) {
      bf16x8 af[4], bfr[4];
#pragma unroll
      for (int m = 0; m < 4; ++m) {
        int row = wr * 64 + m * 16 + lm;
        int slot = (kk * 4 + lk) ^ (row & 7);
        af[m] = *(const bf16x8*)(AsB + row * 128 + slot * 16);
      }
#pragma unroll
      for (int n = 0; n < 4; ++n) {
        int row = wc * 64 + n * 16 + lm;
        int slot = (kk * 4 + lk) ^ (row & 7);
        bfr[n] = *(const bf16x8*)(BsB + row * 128 + slot * 16);
      }
#pragma unroll
      for (int m = 0; m < 4; ++m)
#pragma unroll
        for (int n = 0; n < 4; ++n)
          acc[m][n] = __builtin_amdgcn_mfma_f32_16x16x32_bf16(af[m], bfr[n],
                                                              acc[m][n], 0, 0, 0);
    }
    __syncthreads();  // protect LDS before next stage
  }

  // C/D layout: col = lane&15, row = (lane>>4)*4 + reg
  unsigned short* P = part + (size_t)kc * B_DIM * E_DIM;
#pragma unroll
  for (int m = 0; m < 4; ++m) {
    int r = row0 + wr * 64 + m * 16 + lk * 4;
#pragma unroll
    for (int n = 0; n < 4; ++n) {
      int c = col0 + wc * 64 + n * 16 + lm;
#pragma unroll
      for (int q = 0; q < 4; ++q) {
        P[(size_t)(r + q) * E_DIM + c] = f2bf(acc[m][n][q]);
      }
    }
  }
}

// ---------------- stage 2b: reduce bf16 split-K partials -------------------
__global__ __launch_bounds__(256) void reduce_part(
    const unsigned short* __restrict__ part, float* __restrict__ C) {
  const size_t i = ((size_t)blockIdx.x * 256 + threadIdx.x) * 8;
  const size_t n = (size_t)B_DIM * E_DIM;
  float e[8] = {};
#pragma unroll
  for (int p = 0; p < KSPLIT; ++p) {
    uint4 v = *reinterpret_cast<const uint4*>(part + p * n + i);
    unsigned w[4] = {v.x, v.y, v.z, v.w};
#pragma unroll
    for (int q = 0; q < 4; ++q) {
      e[2 * q] += bfl(w[q]);
      e[2 * q + 1] += bfh(w[q]);
    }
  }
  float4 o0 = {e[0], e[1], e[2], e[3]};
  float4 o1 = {e[4], e[5], e[6], e[7]};
  *reinterpret_cast<float4*>(C + i) = o0;
  *reinterpret_cast<float4*>(C + i + 4) = o1;
}

extern "C" void kernel_launch(void* const* d_in, const int* in_sizes, int n_in,
                              void* d_out, int out_size, void* d_ws, size_t ws_size,
                              hipStream_t stream) {
  const float* x = (const float*)d_in[0];
  const float* W = (const float*)d_in[1];
  const float* w_elem = (const float*)d_in[2];
  const int* perm = (const int*)d_in[3];
  const int* segid = (const int*)d_in[4];
  const int* agg = (const int*)d_in[5];
  float* out = (float*)d_out;

  char* ws = (char*)d_ws;
  unsigned short* y = (unsigned short*)ws;  // B*G bf16 = 16 MB
  unsigned short* Wb =
      (unsigned short*)(ws + (size_t)B_DIM * G_DIM * 2);  // E*G bf16 = 8 MB
  unsigned short* part =
      (unsigned short*)(ws + (size_t)B_DIM * G_DIM * 2 +
                        (size_t)E_DIM * G_DIM * 2);  // 4*B*E bf16 = 16 MB
  unsigned* meta1 =
      (unsigned*)((char*)part + (size_t)KSPLIT * B_DIM * E_DIM * 2);
  unsigned* metaH = (unsigned*)((char*)meta1 + (size_t)S_DIM * 4);
  unsigned short* metaG = (unsigned short*)((char*)metaH + (S_DIM / 32) * 4);

  hipLaunchKernelGGL(setup, dim3(132), dim3(256), 0, stream, w_elem, perm,
                     segid, agg, meta1, metaH, metaG);
  hipLaunchKernelGGL(seg_reduce, dim3(B_DIM + 1024), dim3(1024), 0, stream, x,
                     meta1, metaH, metaG, agg, y, W, Wb);
  hipLaunchKernelGGL(gemm_bt, dim3(E_DIM / 128, B_DIM / 128, KSPLIT),
                     dim3(256), 0, stream, y, Wb, part);
  hipLaunchKernelGGL(reduce_part,
                     dim3(((size_t)B_DIM * E_DIM / 8) / 256), dim3(256), 0,
                     stream, part, out);
}

// Round 17
// 112.153 us; speedup vs baseline: 1.2628x; 1.0148x over previous
//
#include <hip/hip_runtime.h>
#include <hip/hip_bf16.h>

#define B_DIM 2048
#define S_DIM 32768
#define G_DIM 4096
#define E_DIM 1024
#define KSPLIT 4
#define KCHUNK (G_DIM / KSPLIT)

typedef __bf16 bf16x8 __attribute__((ext_vector_type(8)));
typedef float f32x4 __attribute__((ext_vector_type(4)));

__device__ __forceinline__ unsigned short f2bf(float f) {
  unsigned int u = __builtin_bit_cast(unsigned int, f);
  u += 0x7FFFu + ((u >> 16) & 1u);   // round-to-nearest-even (no NaN inputs here)
  return (unsigned short)(u >> 16);
}

__device__ __forceinline__ float bfl(unsigned u) {
  return __builtin_bit_cast(float, u << 16);
}
__device__ __forceinline__ float bfh(unsigned u) {
  return __builtin_bit_cast(float, u & 0xFFFF0000u);
}

__device__ __forceinline__ void async16(void* lds, const void* g) {
  __builtin_amdgcn_global_load_lds(
      (const __attribute__((address_space(1))) unsigned int*)g,
      (__attribute__((address_space(3))) unsigned int*)lds, 16, 0, 0);
}

// Non-returning LDS float atomic add (ds_add_f32). Invisible to the
// compiler's waitcnt model: must be drained with an explicit
// s_waitcnt lgkmcnt(0) before any barrier that readers wait on.
__device__ __forceinline__ void lds_add(float* p, float v) {
  unsigned off = (unsigned)(size_t)(__attribute__((address_space(3))) float*)p;
  asm volatile("ds_add_f32 %0, %1" :: "v"(off), "v"(v));
}

// ---------------- setup: meta1 + run-head masks in ONE kernel ---------------
__global__ __launch_bounds__(256) void setup(
    const float* __restrict__ w_elem, const int* __restrict__ perm,
    const int* __restrict__ segid, const int* __restrict__ agg,
    unsigned* __restrict__ meta1, unsigned* __restrict__ metaH,
    unsigned short* __restrict__ metaG) {
  const int blk = blockIdx.x;
  const int tid = threadIdx.x;
  if (blk < 128) {  // setup_meta
    int s = blk * 256 + tid;
    int g = segid[s];
    int a = agg[g];
    float cm = (a == 0) ? 1.0f : (a == 2 ? w_elem[s] : 0.0f);
    meta1[s] = (unsigned)perm[s] | (a == 1 ? 0x8000u : 0u) |
               ((unsigned)f2bf(cm) << 16);
  } else {  // setup_runs
    int t = (blk - 128) * 256 + tid;
    int s0 = t * 32;
    int prev = (s0 == 0) ? -1 : segid[s0 - 1];
    unsigned m = 0;
#pragma unroll
    for (int c = 0; c < 8; ++c) {
      int4 gw = *reinterpret_cast<const int4*>(segid + s0 + c * 4);
      if (gw.x != prev) m |= 1u << (c * 4 + 0);
      if (gw.y != gw.x) m |= 1u << (c * 4 + 1);
      if (gw.z != gw.y) m |= 1u << (c * 4 + 2);
      if (gw.w != gw.z) m |= 1u << (c * 4 + 3);
      prev = gw.w;
    }
    metaH[t] = m;
    metaG[t] = (unsigned short)segid[s0];
  }
}

// ---------------- stage 1: 1 row/block, 2 barriers, wave-scan combine ------
// R16 body; stage loop restructured to issue ALL 8 float4 loads before any
// pack/ds_write (max outstanding loads; nothing else live pre-barrier).
__global__ __launch_bounds__(1024, 8) void seg_reduce(
    const float* __restrict__ x, const unsigned* __restrict__ meta1,
    const unsigned* __restrict__ metaH, const unsigned short* __restrict__ metaG,
    const int* __restrict__ agg, unsigned short* __restrict__ y,
    const float* __restrict__ W, unsigned short* __restrict__ Wb) {
  __shared__ __align__(16) unsigned short xrow[S_DIM];  // 64 KB (bf16)
  __shared__ float acc[G_DIM];                          // 16 KB
  const int t = threadIdx.x;
  const int b = blockIdx.x;
  const unsigned lane = t & 63;

  if (b >= B_DIM) {  // conv_w block (uniform branch, no barriers used)
    size_t i = ((size_t)(b - B_DIM) * 1024 + t) * 4;
    float4 v = *reinterpret_cast<const float4*>(W + i);
    ushort4 o;
    o.x = f2bf(v.x);
    o.y = f2bf(v.y);
    o.z = f2bf(v.z);
    o.w = f2bf(v.w);
    *reinterpret_cast<ushort4*>(Wb + i) = o;
    return;
  }

#pragma unroll
  for (int i = 0; i < G_DIM / 1024; ++i) acc[t + i * 1024] = 0.0f;

  const unsigned mrun = metaH[t];
  const bool fp = (mrun & 1u) != 0;  // run head exactly at my window start
  const int g0 = metaG[t];
  int g = g0;

  // stage full row as bf16: issue ALL loads first, then pack+write
  const float4* xg = reinterpret_cast<const float4*>(x + (size_t)b * S_DIM);
  float4 v[8];
#pragma unroll
  for (int i = 0; i < 8; ++i) v[i] = xg[i * 1024 + t];
#pragma unroll
  for (int i = 0; i < 8; ++i) {
    unsigned short h0 = __builtin_bit_cast(unsigned short, (__bf16)v[i].x);
    unsigned short h1 = __builtin_bit_cast(unsigned short, (__bf16)v[i].y);
    unsigned short h2 = __builtin_bit_cast(unsigned short, (__bf16)v[i].z);
    unsigned short h3 = __builtin_bit_cast(unsigned short, (__bf16)v[i].w);
    uint2 p;
    p.x = (unsigned)h0 | ((unsigned)h1 << 16);
    p.y = (unsigned)h2 | ((unsigned)h3 << 16);
    *reinterpret_cast<uint2*>(&xrow[(i * 1024 + t) * 4]) = p;
  }
  __syncthreads();  // B1: xrow + acc zero visible

  const int s0 = t * 32;
  float sum = 0.0f, lead = 0.0f;
  int nf = 0;

  for (int h = 0; h < 2; ++h) {  // two halves of 16 elems
    const int sb = s0 + h * 16;
    uint4 ma = *reinterpret_cast<const uint4*>(meta1 + sb);
    uint4 mb = *reinterpret_cast<const uint4*>(meta1 + sb + 4);
    uint4 mc = *reinterpret_cast<const uint4*>(meta1 + sb + 8);
    uint4 md = *reinterpret_cast<const uint4*>(meta1 + sb + 12);
    unsigned m[16] = {ma.x, ma.y, ma.z, ma.w, mb.x, mb.y, mb.z, mb.w,
                      mc.x, mc.y, mc.z, mc.w, md.x, md.y, md.z, md.w};
    unsigned short xu[16];
#pragma unroll
    for (int j = 0; j < 16; ++j) xu[j] = xrow[m[j] & 0x7FFF];
    const unsigned mh = mrun >> (h * 16);
#pragma unroll
    for (int j = 0; j < 16; ++j) {
      if (h + j > 0 && (mh & (1u << j))) {  // run head: close previous run
        if (nf == 0 && !fp) {
          lead = sum;  // portion of a run that started in an earlier thread
        } else {
          acc[g] = sum;  // run started & ended inside my window: exclusive
        }
        ++nf;
        sum = 0.0f;
        ++g;
      }
      float xv = bfl((unsigned)xu[j]);
      float cm = bfh(m[j]);
      float vv = (m[j] & 0x8000u) ? (xu[j] ? 1.0f : 0.0f) : xv * cm;
      sum += vv;
    }
  }
  // per-thread summary: myLead = collectable-by-predecessor portion,
  // sum = trailing-run partial (group g), F = has a run head (stops scan)
  float myLead = fp ? 0.0f : (nf == 0 ? sum : lead);
  const int F = (mrun != 0);

  // segmented suffix scan over lanes
  float s = myLead;
  int o = !F;
#pragma unroll
  for (int d = 1; d <= 32; d <<= 1) {
    float sd = __shfl_down(s, d);
    int od = __shfl_down(o, d);
    const bool valid = lane + d < 64;
    sd = valid ? sd : 0.0f;
    od = valid ? od : 1;  // virtual lanes: open, contribute 0
    s += o ? sd : 0.0f;
    o &= od;
  }
  float s1 = __shfl_down(s, 1);
  int o1 = __shfl_down(o, 1);
  if (lane == 63) {
    s1 = 0.0f;
    o1 = 1;
  }

  if (mrun != 0) {  // owner of my trailing run
    float tot = sum + s1;
    if (o1) {
      lds_add(&acc[g], tot);  // run continues into the next wave
    } else {
      acc[g] = tot;  // run closed within this wave: exclusive write
    }
  }
  if (lane == 0 && !fp) {
    lds_add(&acc[g0], s);  // wave-leading portion of an incoming run
  }

  // Drain asm ds_adds (invisible to compiler waitcnt model) before barrier.
  asm volatile("s_waitcnt lgkmcnt(0)" ::: "memory");
  __syncthreads();  // B2

#pragma unroll
  for (int i = 0; i < G_DIM / 1024; ++i) {
    int g2 = t + i * 1024;
    float vv = acc[g2];
    if (agg[g2] == 1) vv = (vv > 0.0f) ? 1.0f : 0.0f;  // acc holds nnz count
    vv = fmaxf(vv, 0.0f);                               // relu
    y[(size_t)b * G_DIM + g2] = f2bf(vv);
  }
}

// ---------------- stage 2a: split-K GEMM, 128x128 tile + XCD swizzle -------
// Bijective XCD remap: linear id -> (id&7)*64 + id>>3, so each XCD executes
// a contiguous 64-block range sharing ~4 MB of A/B panels (~= its L2).
__global__ __launch_bounds__(256) void gemm_bt(
    const unsigned short* __restrict__ A,   // y bf16 [B_DIM][G_DIM]
    const unsigned short* __restrict__ Bw,  // W bf16 [E_DIM][G_DIM]
    unsigned short* __restrict__ part) {    // [KSPLIT][B_DIM][E_DIM] bf16
  __shared__ __align__(16) unsigned short As[128 * 64];  // 16 KB
  __shared__ __align__(16) unsigned short Bs[128 * 64];  // 16 KB
  const int t = threadIdx.x;
  const int lane = t & 63;
  const int wid = t >> 6;
  const int wr = wid >> 1;  // wave row (M): 0..1, owns 64 rows
  const int wc = wid & 1;   // wave col (N): 0..1, owns 64 cols

  // XCD-bijective swizzle of the 512-block linear id (8 x 16 x KSPLIT grid)
  const int id = blockIdx.x + 8 * (blockIdx.y + 16 * blockIdx.z);
  const int nid = (id & 7) * 64 + (id >> 3);
  const int bx = nid & 7;
  const int by = (nid >> 3) & 15;
  const int kc = nid >> 7;
  const int row0 = by * 128;
  const int col0 = bx * 128;

  // staging: round i covers LDS bytes i*4096 + t*16 -> row = i*32 + (t>>3),
  // slot = t&7. Inverse-swizzled k offset (round-invariant: 32 % 8 == 0).
  const int r_ = t >> 3;  // 0..31 (round-local row base)
  const int ksw = ((t & 7) ^ (r_ & 7)) * 8;  // elements
  const unsigned short* Ag[4];
  const unsigned short* Bg[4];
#pragma unroll
  for (int i = 0; i < 4; ++i) {
    Ag[i] = A + (size_t)(row0 + i * 32 + r_) * G_DIM + ksw;
    Bg[i] = Bw + (size_t)(col0 + i * 32 + r_) * G_DIM + ksw;
  }
  char* AsB = (char*)As;
  char* BsB = (char*)Bs;
  char* dA[4];
  char* dB[4];
#pragma unroll
  for (int i = 0; i < 4; ++i) {
    dA[i] = AsB + i * 4096 + wid * 1024;  // wave-uniform LDS dst bases
    dB[i] = BsB + i * 4096 + wid * 1024;
  }

  const int lm = lane & 15;
  const int lk = lane >> 4;  // 0..3

  f32x4 acc[4][4] = {};

  for (int kt = kc * KCHUNK; kt < (kc + 1) * KCHUNK; kt += 64) {
#pragma unroll
    for (int i = 0; i < 4; ++i) {
      async16(dA[i], Ag[i] + kt);
      async16(dB[i], Bg[i] + kt);
    }
    __syncthreads();  // drains vmcnt before barrier
#pragma unroll
    for (int kk = 0; kk < 2; ++kk) {
      bf16x8 af[4], bfr[4];
#pragma unroll
      for (int m = 0; m < 4; ++m) {
        int row = wr * 64 + m * 16 + lm;
        int slot = (kk * 4 + lk) ^ (row & 7);
        af[m] = *(const bf16x8*)(AsB + row * 128 + slot * 16);
      }
#pragma unroll
      for (int n = 0; n < 4; ++n) {
        int row = wc * 64 + n * 16 + lm;
        int slot = (kk * 4 + lk) ^ (row & 7);
        bfr[n] = *(const bf16x8*)(BsB + row * 128 + slot * 16);
      }
#pragma unroll
      for (int m = 0; m < 4; ++m)
#pragma unroll
        for (int n = 0; n < 4; ++n)
          acc[m][n] = __builtin_amdgcn_mfma_f32_16x16x32_bf16(af[m], bfr[n],
                                                              acc[m][n], 0, 0, 0);
    }
    __syncthreads();  // protect LDS before next stage
  }

  // C/D layout: col = lane&15, row = (lane>>4)*4 + reg
  unsigned short* P = part + (size_t)kc * B_DIM * E_DIM;
#pragma unroll
  for (int m = 0; m < 4; ++m) {
    int r = row0 + wr * 64 + m * 16 + lk * 4;
#pragma unroll
    for (int n = 0; n < 4; ++n) {
      int c = col0 + wc * 64 + n * 16 + lm;
#pragma unroll
      for (int q = 0; q < 4; ++q) {
        P[(size_t)(r + q) * E_DIM + c] = f2bf(acc[m][n][q]);
      }
    }
  }
}

// ---------------- stage 2b: reduce bf16 split-K partials -------------------
__global__ __launch_bounds__(256) void reduce_part(
    const unsigned short* __restrict__ part, float* __restrict__ C) {
  const size_t i = ((size_t)blockIdx.x * 256 + threadIdx.x) * 8;
  const size_t n = (size_t)B_DIM * E_DIM;
  float e[8] = {};
#pragma unroll
  for (int p = 0; p < KSPLIT; ++p) {
    uint4 v = *reinterpret_cast<const uint4*>(part + p * n + i);
    unsigned w[4] = {v.x, v.y, v.z, v.w};
#pragma unroll
    for (int q = 0; q < 4; ++q) {
      e[2 * q] += bfl(w[q]);
      e[2 * q + 1] += bfh(w[q]);
    }
  }
  float4 o0 = {e[0], e[1], e[2], e[3]};
  float4 o1 = {e[4], e[5], e[6], e[7]};
  *reinterpret_cast<float4*>(C + i) = o0;
  *reinterpret_cast<float4*>(C + i + 4) = o1;
}

extern "C" void kernel_launch(void* const* d_in, const int* in_sizes, int n_in,
                              void* d_out, int out_size, void* d_ws, size_t ws_size,
                              hipStream_t stream) {
  const float* x = (const float*)d_in[0];
  const float* W = (const float*)d_in[1];
  const float* w_elem = (const float*)d_in[2];
  const int* perm = (const int*)d_in[3];
  const int* segid = (const int*)d_in[4];
  const int* agg = (const int*)d_in[5];
  float* out = (float*)d_out;

  char* ws = (char*)d_ws;
  unsigned short* y = (unsigned short*)ws;  // B*G bf16 = 16 MB
  unsigned short* Wb =
      (unsigned short*)(ws + (size_t)B_DIM * G_DIM * 2);  // E*G bf16 = 8 MB
  unsigned short* part =
      (unsigned short*)(ws + (size_t)B_DIM * G_DIM * 2 +
                        (size_t)E_DIM * G_DIM * 2);  // 4*B*E bf16 = 16 MB
  unsigned* meta1 =
      (unsigned*)((char*)part + (size_t)KSPLIT * B_DIM * E_DIM * 2);
  unsigned* metaH = (unsigned*)((char*)meta1 + (size_t)S_DIM * 4);
  unsigned short* metaG = (unsigned short*)((char*)metaH + (S_DIM / 32) * 4);

  hipLaunchKernelGGL(setup, dim3(132), dim3(256), 0, stream, w_elem, perm,
                     segid, agg, meta1, metaH, metaG);
  hipLaunchKernelGGL(seg_reduce, dim3(B_DIM + 1024), dim3(1024), 0, stream, x,
                     meta1, metaH, metaG, agg, y, W, Wb);
  hipLaunchKernelGGL(gemm_bt, dim3(E_DIM / 128, B_DIM / 128, KSPLIT),
                     dim3(256), 0, stream, y, Wb, part);
  hipLaunchKernelGGL(reduce_part,
                     dim3(((size_t)B_DIM * E_DIM / 8) / 256), dim3(256), 0,
                     stream, part, out);
}